// Round 1
// 859.088 us; speedup vs baseline: 1.3000x; 1.3000x over previous
//
#include <hip/hip_runtime.h>
#include <hip/hip_bf16.h>
#include <math.h>

// Problem constants
#define T_TOK 512
#define H_DIM 2048
#define E_NUM 16
#define K_TOP 4
#define I_DIM 1408
#define IS_DIM 2816

typedef __bf16 bf16;
typedef __attribute__((ext_vector_type(8))) __bf16 bf16x8;
typedef __attribute__((ext_vector_type(4))) float f32x4;

// GEMM tiling: 64x64 tiles -> ~4x the active blocks vs 128x128.
// With count_e ~ 128 per expert, routed gateup now fields ~704 active blocks
// (vs 176), giving ~11 waves/CU to hide HBM latency.
#define BM 64
#define BN 64
#define BK 64

// Load 8 contiguous f32 and convert to bf16x8 (two dwordx4 loads + cvt).
__device__ inline bf16x8 cvt8(const float* __restrict__ p) {
    const f32x4 a = *(const f32x4*)(p);
    const f32x4 b = *(const f32x4*)(p + 4);
    bf16x8 r;
    r[0] = (bf16)a[0]; r[1] = (bf16)a[1]; r[2] = (bf16)a[2]; r[3] = (bf16)a[3];
    r[4] = (bf16)b[0]; r[5] = (bf16)b[1]; r[6] = (bf16)b[2]; r[7] = (bf16)b[3];
    return r;
}

// ---------------------------------------------------------------------------
// Router: logits = x @ gate_w.T in full f32; softmax -> top4 -> renormalize.
// One wave per token. Softmax denominator cancels under top-k renorm.
// ---------------------------------------------------------------------------
__global__ __launch_bounds__(64) void router_kernel(
    const float* __restrict__ x, const float* __restrict__ gw,
    int* __restrict__ counts, int* __restrict__ tok_id, float* __restrict__ tok_w)
{
    int t = blockIdx.x;
    int lane = threadIdx.x;
    float acc[E_NUM];
#pragma unroll
    for (int e = 0; e < E_NUM; e++) acc[e] = 0.f;
    for (int h = lane; h < H_DIM; h += 64) {
        float xv = x[t * H_DIM + h];
#pragma unroll
        for (int e = 0; e < E_NUM; e++) acc[e] += xv * gw[e * H_DIM + h];
    }
#pragma unroll
    for (int e = 0; e < E_NUM; e++) {
#pragma unroll
        for (int off = 32; off; off >>= 1) acc[e] += __shfl_xor(acc[e], off);
    }
    if (lane == 0) {
        float m = acc[0];
#pragma unroll
        for (int e = 1; e < E_NUM; e++) m = fmaxf(m, acc[e]);
        float p[E_NUM];
#pragma unroll
        for (int e = 0; e < E_NUM; e++) p[e] = __expf(acc[e] - m);
        int sel[K_TOP];
        float pw[K_TOP];
        float wsum = 0.f;
        bool used[E_NUM];
#pragma unroll
        for (int e = 0; e < E_NUM; e++) used[e] = false;
        for (int k = 0; k < K_TOP; k++) {
            int best = 0;
            float bv = -1.f;
            for (int e = 0; e < E_NUM; e++) {
                if (!used[e] && p[e] > bv) { bv = p[e]; best = e; }
            }
            used[best] = true;
            sel[k] = best;
            pw[k] = bv;
            wsum += bv;
        }
        float inv = 1.f / wsum;
        for (int k = 0; k < K_TOP; k++) {
            int e = sel[k];
            int pos = atomicAdd(&counts[e], 1);
            tok_id[e * T_TOK + pos] = t;
            tok_w[e * T_TOK + pos] = pw[k] * inv;  // SCALE == 1.0
        }
    }
}

// ---------------------------------------------------------------------------
// gate_up GEMM (paired): C_g = A @ Wg^T, C_u = A @ Wu^T, out = silu(g)*u*wgt.
// 64x64 tile, BK=64, 4 waves of 32x32. LDS rows XOR-swizzled
// (16B-chunk ^= row&7) so ds_write_b128 / ds_read_b128 are <=2-way (free).
// ---------------------------------------------------------------------------
template <bool GATHER>
__global__ __launch_bounds__(256) void gateup_kernel(
    const float* __restrict__ X,       // [T,H] f32
    const float* __restrict__ W,       // expert-strided gate_up weights, f32
    long w_expert_stride,              // elements per expert (2I*H) or 0
    int pair_off_rows,                 // I or IS (u-row offset)
    bf16* __restrict__ Hout,           // output intermediate (bf16 ws)
    long h_expert_stride,              // T*I or 0
    int ldh,                           // I or IS
    const int* __restrict__ counts,
    const int* __restrict__ tok_id,
    const float* __restrict__ tok_w)
{
    int e = blockIdx.z;
    int n0 = blockIdx.x * BN;
    int m0 = blockIdx.y * BM;
    int count;
    if constexpr (GATHER) count = counts[e]; else count = T_TOK;
    if (m0 >= count) return;

    const float* Wg = W + (long)e * w_expert_stride;
    const float* Wu = Wg + (long)pair_off_rows * H_DIM;
    bf16* Ho = Hout + (long)e * h_expert_stride;
    const int* tid_p = nullptr;
    const float* tw_p = nullptr;
    if constexpr (GATHER) {
        tid_p = tok_id + e * T_TOK;
        tw_p = tok_w + e * T_TOK;
    }

    __shared__ bf16 sA[BM * BK];
    __shared__ bf16 sG[BN * BK];
    __shared__ bf16 sU[BN * BK];

    int tidx = threadIdx.x;
    int lane = tidx & 63;
    int wv = tidx >> 6;
    int wm = wv >> 1, wn = wv & 1;

    f32x4 accG[2][2], accU[2][2];
#pragma unroll
    for (int i = 0; i < 2; i++)
#pragma unroll
        for (int j = 0; j < 2; j++) {
            accG[i][j] = (f32x4){0.f, 0.f, 0.f, 0.f};
            accU[i][j] = (f32x4){0.f, 0.f, 0.f, 0.f};
        }

    // Staging: tile = 4096 bf16 = 512 chunks of 8 elems; thread stages chunks
    // tidx and tidx+256. chunk c -> row c>>3, 16B-chunk col (c&7), swizzled.
    long arow_off[2], wrow_off[2];
    int lds_off[2];
#pragma unroll
    for (int c2 = 0; c2 < 2; c2++) {
        int c = tidx + c2 * 256;
        int row = c >> 3, col8 = c & 7;
        int tok;
        if constexpr (GATHER) {
            int idx = m0 + row;
            tok = (idx < count) ? tid_p[idx] : tid_p[0];
        } else {
            tok = m0 + row;
        }
        arow_off[c2] = (long)tok * H_DIM + col8 * 8;
        wrow_off[c2] = (long)(n0 + row) * H_DIM + col8 * 8;
        lds_off[c2] = row * BK + ((col8 ^ (row & 7)) << 3);
    }

    const int ktiles = H_DIM / BK;
    for (int kt = 0; kt < ktiles; kt++) {
        int k0 = kt * BK;
#pragma unroll
        for (int c2 = 0; c2 < 2; c2++) {
            *(bf16x8*)&sA[lds_off[c2]] = cvt8(&X[arow_off[c2] + k0]);
            *(bf16x8*)&sG[lds_off[c2]] = cvt8(&Wg[wrow_off[c2] + k0]);
            *(bf16x8*)&sU[lds_off[c2]] = cvt8(&Wu[wrow_off[c2] + k0]);
        }
        __syncthreads();
        int quad = lane >> 4, l16 = lane & 15;
        bf16x8 aF[2][2], gF[2][2], uF[2][2];
#pragma unroll
        for (int mt = 0; mt < 2; mt++) {
            int r = wm * 32 + mt * 16 + l16;
            int rb = r * BK, rx = r & 7;
#pragma unroll
            for (int ks = 0; ks < 2; ks++)
                aF[mt][ks] = *(const bf16x8*)&sA[rb + (((ks * 4 + quad) ^ rx) << 3)];
        }
#pragma unroll
        for (int nt = 0; nt < 2; nt++) {
            int r = wn * 32 + nt * 16 + l16;
            int rb = r * BK, rx = r & 7;
#pragma unroll
            for (int ks = 0; ks < 2; ks++) {
                gF[nt][ks] = *(const bf16x8*)&sG[rb + (((ks * 4 + quad) ^ rx) << 3)];
                uF[nt][ks] = *(const bf16x8*)&sU[rb + (((ks * 4 + quad) ^ rx) << 3)];
            }
        }
#pragma unroll
        for (int ks = 0; ks < 2; ks++)
#pragma unroll
            for (int mt = 0; mt < 2; mt++)
#pragma unroll
                for (int nt = 0; nt < 2; nt++) {
                    accG[mt][nt] = __builtin_amdgcn_mfma_f32_16x16x32_bf16(aF[mt][ks], gF[nt][ks], accG[mt][nt], 0, 0, 0);
                    accU[mt][nt] = __builtin_amdgcn_mfma_f32_16x16x32_bf16(aF[mt][ks], uF[nt][ks], accU[mt][nt], 0, 0, 0);
                }
        __syncthreads();
    }

    // Epilogue: h = silu(g)*u*wgt, stored bf16. C/D layout: col=lane&15, row=quad*4+r.
    int quad = lane >> 4, l16 = lane & 15;
#pragma unroll
    for (int mt = 0; mt < 2; mt++) {
#pragma unroll
        for (int r = 0; r < 4; r++) {
            int row = m0 + wm * 32 + mt * 16 + quad * 4 + r;
            if (row < count) {
                float wgt = 1.f;
                if constexpr (GATHER) wgt = tw_p[row];
#pragma unroll
                for (int nt = 0; nt < 2; nt++) {
                    int col = n0 + wn * 32 + nt * 16 + l16;
                    float g = accG[mt][nt][r];
                    float u = accU[mt][nt][r];
                    float sig = 1.f / (1.f + __expf(-g));
                    float h = g * sig * u * wgt;
                    Ho[(long)row * ldh + col] = (bf16)h;
                }
            }
        }
    }
}

// ---------------------------------------------------------------------------
// down GEMM: C = A @ Wd^T. A = bf16 intermediate (direct 16B LDS copy),
// W = f32 weights (cvt during staging). GATHER: scatter-atomicAdd to
// out[token] (f32). !GATHER: plain f32 store (runs first, initializes out).
// ---------------------------------------------------------------------------
template <bool GATHER>
__global__ __launch_bounds__(256) void down_kernel(
    const bf16* __restrict__ Hin,      // intermediate base (bf16)
    long h_expert_stride, int ldh, int Kdim,
    const float* __restrict__ W,       // down weights f32, rows along Kdim
    long w_expert_stride,
    float* __restrict__ out,           // [T,H] f32 output
    const int* __restrict__ counts,
    const int* __restrict__ tok_id)
{
    int e = blockIdx.z;
    int n0 = blockIdx.x * BN;   // over H_DIM
    int m0 = blockIdx.y * BM;
    int count;
    if constexpr (GATHER) count = counts[e]; else count = T_TOK;
    if (m0 >= count) return;

    const bf16* A = Hin + (long)e * h_expert_stride;
    const float* B = W + (long)e * w_expert_stride;
    const int* tid_p = nullptr;
    if constexpr (GATHER) tid_p = tok_id + e * T_TOK;

    __shared__ bf16 sA[BM * BK];
    __shared__ bf16 sB[BN * BK];

    int tidx = threadIdx.x;
    int lane = tidx & 63;
    int wv = tidx >> 6;
    int wm = wv >> 1, wn = wv & 1;

    f32x4 acc[2][2];
#pragma unroll
    for (int i = 0; i < 2; i++)
#pragma unroll
        for (int j = 0; j < 2; j++) acc[i][j] = (f32x4){0.f, 0.f, 0.f, 0.f};

    long arow_off[2], brow_off[2];
    int lds_off[2];
#pragma unroll
    for (int c2 = 0; c2 < 2; c2++) {
        int c = tidx + c2 * 256;
        int row = c >> 3, col8 = c & 7;
        arow_off[c2] = (long)(m0 + row) * ldh + col8 * 8;
        brow_off[c2] = (long)(n0 + row) * Kdim + col8 * 8;
        lds_off[c2] = row * BK + ((col8 ^ (row & 7)) << 3);
    }

    const int ktiles = Kdim / BK;
    for (int kt = 0; kt < ktiles; kt++) {
        int k0 = kt * BK;
#pragma unroll
        for (int c2 = 0; c2 < 2; c2++) {
            *(bf16x8*)&sA[lds_off[c2]] = *(const bf16x8*)&A[arow_off[c2] + k0];
            *(bf16x8*)&sB[lds_off[c2]] = cvt8(&B[brow_off[c2] + k0]);
        }
        __syncthreads();
        int quad = lane >> 4, l16 = lane & 15;
        bf16x8 aF[2][2], bF[2][2];
#pragma unroll
        for (int mt = 0; mt < 2; mt++) {
            int r = wm * 32 + mt * 16 + l16;
            int rb = r * BK, rx = r & 7;
#pragma unroll
            for (int ks = 0; ks < 2; ks++)
                aF[mt][ks] = *(const bf16x8*)&sA[rb + (((ks * 4 + quad) ^ rx) << 3)];
        }
#pragma unroll
        for (int nt = 0; nt < 2; nt++) {
            int r = wn * 32 + nt * 16 + l16;
            int rb = r * BK, rx = r & 7;
#pragma unroll
            for (int ks = 0; ks < 2; ks++)
                bF[nt][ks] = *(const bf16x8*)&sB[rb + (((ks * 4 + quad) ^ rx) << 3)];
        }
#pragma unroll
        for (int ks = 0; ks < 2; ks++)
#pragma unroll
            for (int mt = 0; mt < 2; mt++)
#pragma unroll
                for (int nt = 0; nt < 2; nt++)
                    acc[mt][nt] = __builtin_amdgcn_mfma_f32_16x16x32_bf16(aF[mt][ks], bF[nt][ks], acc[mt][nt], 0, 0, 0);
        __syncthreads();
    }

    int quad = lane >> 4, l16 = lane & 15;
#pragma unroll
    for (int mt = 0; mt < 2; mt++) {
#pragma unroll
        for (int r = 0; r < 4; r++) {
            int row = m0 + wm * 32 + mt * 16 + quad * 4 + r;
            if (row < count) {
#pragma unroll
                for (int nt = 0; nt < 2; nt++) {
                    int col = n0 + wn * 32 + nt * 16 + l16;
                    float v = acc[mt][nt][r];
                    if constexpr (GATHER) {
                        int tok = tid_p[row];
                        atomicAdd(&out[(long)tok * H_DIM + col], v);
                    } else {
                        out[(long)row * H_DIM + col] = v;
                    }
                }
            }
        }
    }
}

// ---------------------------------------------------------------------------
// Workspace layout (bytes):
//   0        counts        (E ints, padded to 256)
//   256      tok_id        (E*T ints   = 32768)
//   33024    tok_w         (E*T floats = 32768)
//   65792    hshared       (T*IS bf16  = 2883584)
//   2949376  hrouted       (E*T*I bf16 = 23068672)
//   total ~26.0 MB
// ---------------------------------------------------------------------------
extern "C" void kernel_launch(void* const* d_in, const int* in_sizes, int n_in,
                              void* d_out, int out_size, void* d_ws, size_t ws_size,
                              hipStream_t stream)
{
    const float* x              = (const float*)d_in[0];
    const float* gate_w         = (const float*)d_in[1];
    const float* w_gate_up      = (const float*)d_in[2];
    const float* w_down         = (const float*)d_in[3];
    const float* shared_gate_up = (const float*)d_in[4];
    const float* shared_down    = (const float*)d_in[5];
    float* out = (float*)d_out;

    char* ws = (char*)d_ws;
    int*   counts  = (int*)(ws + 0);
    int*   tok_id  = (int*)(ws + 256);
    float* tok_w   = (float*)(ws + 33024);
    bf16*  hshared = (bf16*)(ws + 65792);
    bf16*  hrouted = (bf16*)(ws + 2949376);

    hipMemsetAsync(counts, 0, E_NUM * sizeof(int), stream);

    router_kernel<<<T_TOK, 64, 0, stream>>>(x, gate_w, counts, tok_id, tok_w);

    // shared gate_up: N=IS, K=H; identity rows. 44x8 = 352 blocks.
    gateup_kernel<false><<<dim3(IS_DIM / BN, T_TOK / BM, 1), 256, 0, stream>>>(
        x, shared_gate_up, 0L, IS_DIM, hshared, 0L, IS_DIM, nullptr, nullptr, nullptr);

    // routed gate_up: N=I, K=H; gathered rows, combine weight fused.
    // 22 x 8 x 16 launched; ~22x2x16 = 704 active at count~128.
    gateup_kernel<true><<<dim3(I_DIM / BN, T_TOK / BM, E_NUM), 256, 0, stream>>>(
        x, w_gate_up, (long)2 * I_DIM * H_DIM, I_DIM, hrouted, (long)T_TOK * I_DIM, I_DIM,
        counts, tok_id, tok_w);

    // shared down: K=IS, N=H; plain store initializes out fully. 32x8 = 256 blocks.
    down_kernel<false><<<dim3(H_DIM / BN, T_TOK / BM, 1), 256, 0, stream>>>(
        hshared, 0L, IS_DIM, IS_DIM, shared_down, 0L, out, nullptr, nullptr);

    // routed down: K=I, N=H; atomicAdd scatter by token. ~32x2x16 = 1024 active.
    down_kernel<true><<<dim3(H_DIM / BN, T_TOK / BM, E_NUM), 256, 0, stream>>>(
        hrouted, (long)T_TOK * I_DIM, I_DIM, I_DIM, w_down, (long)H_DIM * I_DIM, out,
        counts, tok_id);
}

// Round 2
// 846.962 us; speedup vs baseline: 1.3186x; 1.0143x over previous
//
#include <hip/hip_runtime.h>
#include <hip/hip_bf16.h>
#include <math.h>

// Problem constants
#define T_TOK 512
#define H_DIM 2048
#define E_NUM 16
#define K_TOP 4
#define I_DIM 1408
#define IS_DIM 2816

typedef __bf16 bf16;
typedef __attribute__((ext_vector_type(8))) __bf16 bf16x8;
typedef __attribute__((ext_vector_type(4))) float f32x4;

// GEMM tiling: 64x64 tiles, BK=64, 4 waves of 32x32 per block.
#define BM 64
#define BN 64
#define BK 64

// Convert two f32x4 (already in registers) to bf16x8.
__device__ inline bf16x8 cvt8v(f32x4 a, f32x4 b) {
    bf16x8 r;
    r[0] = (bf16)a[0]; r[1] = (bf16)a[1]; r[2] = (bf16)a[2]; r[3] = (bf16)a[3];
    r[4] = (bf16)b[0]; r[5] = (bf16)b[1]; r[6] = (bf16)b[2]; r[7] = (bf16)b[3];
    return r;
}

// ---------------------------------------------------------------------------
// Router: logits = x @ gate_w.T in full f32; softmax -> top4 -> renormalize.
// One wave per token. Softmax denominator cancels under top-k renorm.
// ---------------------------------------------------------------------------
__global__ __launch_bounds__(64) void router_kernel(
    const float* __restrict__ x, const float* __restrict__ gw,
    int* __restrict__ counts, int* __restrict__ tok_id, float* __restrict__ tok_w)
{
    int t = blockIdx.x;
    int lane = threadIdx.x;
    float acc[E_NUM];
#pragma unroll
    for (int e = 0; e < E_NUM; e++) acc[e] = 0.f;
    for (int h = lane; h < H_DIM; h += 64) {
        float xv = x[t * H_DIM + h];
#pragma unroll
        for (int e = 0; e < E_NUM; e++) acc[e] += xv * gw[e * H_DIM + h];
    }
#pragma unroll
    for (int e = 0; e < E_NUM; e++) {
#pragma unroll
        for (int off = 32; off; off >>= 1) acc[e] += __shfl_xor(acc[e], off);
    }
    if (lane == 0) {
        float m = acc[0];
#pragma unroll
        for (int e = 1; e < E_NUM; e++) m = fmaxf(m, acc[e]);
        float p[E_NUM];
#pragma unroll
        for (int e = 0; e < E_NUM; e++) p[e] = __expf(acc[e] - m);
        int sel[K_TOP];
        float pw[K_TOP];
        float wsum = 0.f;
        bool used[E_NUM];
#pragma unroll
        for (int e = 0; e < E_NUM; e++) used[e] = false;
        for (int k = 0; k < K_TOP; k++) {
            int best = 0;
            float bv = -1.f;
            for (int e = 0; e < E_NUM; e++) {
                if (!used[e] && p[e] > bv) { bv = p[e]; best = e; }
            }
            used[best] = true;
            sel[k] = best;
            pw[k] = bv;
            wsum += bv;
        }
        float inv = 1.f / wsum;
        for (int k = 0; k < K_TOP; k++) {
            int e = sel[k];
            int pos = atomicAdd(&counts[e], 1);
            tok_id[e * T_TOK + pos] = t;
            tok_w[e * T_TOK + pos] = pw[k] * inv;  // SCALE == 1.0
        }
    }
}

// ---------------------------------------------------------------------------
// gate_up GEMM (paired): C_g = A @ Wg^T, C_u = A @ Wu^T, out = silu(g)*u*wgt.
// 64x64 tile, BK=64, 4 waves of 32x32. LDS rows XOR-swizzled
// (16B-chunk ^= row&7). Reg-staged prefetch: tile kt+1's 12 global loads
// are issued right after tile kt's LDS write, so they stay in flight
// across the MFMA phase and both barriers (pure-streaming kernel; the
// whole game is keeping loads outstanding).
// ---------------------------------------------------------------------------
template <bool GATHER>
__global__ __launch_bounds__(256, 2) void gateup_kernel(
    const float* __restrict__ X,       // [T,H] f32
    const float* __restrict__ W,       // expert-strided gate_up weights, f32
    long w_expert_stride,              // elements per expert (2I*H) or 0
    int pair_off_rows,                 // I or IS (u-row offset)
    bf16* __restrict__ Hout,           // output intermediate (bf16 ws)
    long h_expert_stride,              // T*I or 0
    int ldh,                           // I or IS
    const int* __restrict__ counts,
    const int* __restrict__ tok_id,
    const float* __restrict__ tok_w)
{
    int e = blockIdx.z;
    int n0 = blockIdx.x * BN;
    int m0 = blockIdx.y * BM;
    int count;
    if constexpr (GATHER) count = counts[e]; else count = T_TOK;
    if (m0 >= count) return;

    const float* Wg = W + (long)e * w_expert_stride;
    const float* Wu = Wg + (long)pair_off_rows * H_DIM;
    bf16* Ho = Hout + (long)e * h_expert_stride;
    const int* tid_p = nullptr;
    const float* tw_p = nullptr;
    if constexpr (GATHER) {
        tid_p = tok_id + e * T_TOK;
        tw_p = tok_w + e * T_TOK;
    }

    __shared__ bf16 sA[BM * BK];
    __shared__ bf16 sG[BN * BK];
    __shared__ bf16 sU[BN * BK];

    int tidx = threadIdx.x;
    int lane = tidx & 63;
    int wv = tidx >> 6;
    int wm = wv >> 1, wn = wv & 1;

    f32x4 accG[2][2], accU[2][2];
#pragma unroll
    for (int i = 0; i < 2; i++)
#pragma unroll
        for (int j = 0; j < 2; j++) {
            accG[i][j] = (f32x4){0.f, 0.f, 0.f, 0.f};
            accU[i][j] = (f32x4){0.f, 0.f, 0.f, 0.f};
        }

    // Staging: tile = 4096 bf16 = 512 chunks of 8 elems; thread stages chunks
    // tidx and tidx+256. chunk c -> row c>>3, 16B-chunk col (c&7), swizzled.
    long arow_off[2], wrow_off[2];
    int lds_off[2];
#pragma unroll
    for (int c2 = 0; c2 < 2; c2++) {
        int c = tidx + c2 * 256;
        int row = c >> 3, col8 = c & 7;
        int tok;
        if constexpr (GATHER) {
            int idx = m0 + row;
            tok = (idx < count) ? tid_p[idx] : tid_p[0];
        } else {
            tok = m0 + row;
        }
        arow_off[c2] = (long)tok * H_DIM + col8 * 8;
        wrow_off[c2] = (long)(n0 + row) * H_DIM + col8 * 8;
        lds_off[c2] = row * BK + ((col8 ^ (row & 7)) << 3);
    }

    // Prefetch registers (12 x f32x4 = 48 VGPR in flight).
    f32x4 pA[2][2], pG[2][2], pU[2][2];
#pragma unroll
    for (int c2 = 0; c2 < 2; c2++) {
        pA[c2][0] = *(const f32x4*)&X[arow_off[c2]];
        pA[c2][1] = *(const f32x4*)&X[arow_off[c2] + 4];
        pG[c2][0] = *(const f32x4*)&Wg[wrow_off[c2]];
        pG[c2][1] = *(const f32x4*)&Wg[wrow_off[c2] + 4];
        pU[c2][0] = *(const f32x4*)&Wu[wrow_off[c2]];
        pU[c2][1] = *(const f32x4*)&Wu[wrow_off[c2] + 4];
    }

    const int ktiles = H_DIM / BK;
    for (int kt = 0; kt < ktiles; kt++) {
        __syncthreads();  // all waves done reading the previous tile
        // cvt + LDS write (implicit vmcnt wait on the prefetch loads)
#pragma unroll
        for (int c2 = 0; c2 < 2; c2++) {
            *(bf16x8*)&sA[lds_off[c2]] = cvt8v(pA[c2][0], pA[c2][1]);
            *(bf16x8*)&sG[lds_off[c2]] = cvt8v(pG[c2][0], pG[c2][1]);
            *(bf16x8*)&sU[lds_off[c2]] = cvt8v(pU[c2][0], pU[c2][1]);
        }
        // issue next tile's loads (clamped on last iter; harmless re-read)
        {
            int k0n = (kt + 1 < ktiles) ? (kt + 1) * BK : kt * BK;
#pragma unroll
            for (int c2 = 0; c2 < 2; c2++) {
                pA[c2][0] = *(const f32x4*)&X[arow_off[c2] + k0n];
                pA[c2][1] = *(const f32x4*)&X[arow_off[c2] + k0n + 4];
                pG[c2][0] = *(const f32x4*)&Wg[wrow_off[c2] + k0n];
                pG[c2][1] = *(const f32x4*)&Wg[wrow_off[c2] + k0n + 4];
                pU[c2][0] = *(const f32x4*)&Wu[wrow_off[c2] + k0n];
                pU[c2][1] = *(const f32x4*)&Wu[wrow_off[c2] + k0n + 4];
            }
        }
        __syncthreads();  // LDS writes visible
        int quad = lane >> 4, l16 = lane & 15;
        bf16x8 aF[2][2], gF[2][2], uF[2][2];
#pragma unroll
        for (int mt = 0; mt < 2; mt++) {
            int r = wm * 32 + mt * 16 + l16;
            int rb = r * BK, rx = r & 7;
#pragma unroll
            for (int ks = 0; ks < 2; ks++)
                aF[mt][ks] = *(const bf16x8*)&sA[rb + (((ks * 4 + quad) ^ rx) << 3)];
        }
#pragma unroll
        for (int nt = 0; nt < 2; nt++) {
            int r = wn * 32 + nt * 16 + l16;
            int rb = r * BK, rx = r & 7;
#pragma unroll
            for (int ks = 0; ks < 2; ks++) {
                gF[nt][ks] = *(const bf16x8*)&sG[rb + (((ks * 4 + quad) ^ rx) << 3)];
                uF[nt][ks] = *(const bf16x8*)&sU[rb + (((ks * 4 + quad) ^ rx) << 3)];
            }
        }
#pragma unroll
        for (int ks = 0; ks < 2; ks++)
#pragma unroll
            for (int mt = 0; mt < 2; mt++)
#pragma unroll
                for (int nt = 0; nt < 2; nt++) {
                    accG[mt][nt] = __builtin_amdgcn_mfma_f32_16x16x32_bf16(aF[mt][ks], gF[nt][ks], accG[mt][nt], 0, 0, 0);
                    accU[mt][nt] = __builtin_amdgcn_mfma_f32_16x16x32_bf16(aF[mt][ks], uF[nt][ks], accU[mt][nt], 0, 0, 0);
                }
    }

    // Epilogue: h = silu(g)*u*wgt, stored bf16. C/D layout: col=lane&15, row=quad*4+r.
    int quad = lane >> 4, l16 = lane & 15;
#pragma unroll
    for (int mt = 0; mt < 2; mt++) {
#pragma unroll
        for (int r = 0; r < 4; r++) {
            int row = m0 + wm * 32 + mt * 16 + quad * 4 + r;
            if (row < count) {
                float wgt = 1.f;
                if constexpr (GATHER) wgt = tw_p[row];
#pragma unroll
                for (int nt = 0; nt < 2; nt++) {
                    int col = n0 + wn * 32 + nt * 16 + l16;
                    float g = accG[mt][nt][r];
                    float u = accU[mt][nt][r];
                    float sig = 1.f / (1.f + __expf(-g));
                    float h = g * sig * u * wgt;
                    Ho[(long)row * ldh + col] = (bf16)h;
                }
            }
        }
    }
}

// ---------------------------------------------------------------------------
// down GEMM: C = A @ Wd^T. A = bf16 intermediate (direct 16B LDS copy),
// W = f32 weights (cvt during staging). Same reg-staged prefetch pattern.
// GATHER: scatter-atomicAdd to out[token] (f32). !GATHER: plain f32 store.
// ---------------------------------------------------------------------------
template <bool GATHER>
__global__ __launch_bounds__(256, 3) void down_kernel(
    const bf16* __restrict__ Hin,      // intermediate base (bf16)
    long h_expert_stride, int ldh, int Kdim,
    const float* __restrict__ W,       // down weights f32, rows along Kdim
    long w_expert_stride,
    float* __restrict__ out,           // [T,H] f32 output
    const int* __restrict__ counts,
    const int* __restrict__ tok_id)
{
    int e = blockIdx.z;
    int n0 = blockIdx.x * BN;   // over H_DIM
    int m0 = blockIdx.y * BM;
    int count;
    if constexpr (GATHER) count = counts[e]; else count = T_TOK;
    if (m0 >= count) return;

    const bf16* A = Hin + (long)e * h_expert_stride;
    const float* B = W + (long)e * w_expert_stride;
    const int* tid_p = nullptr;
    if constexpr (GATHER) tid_p = tok_id + e * T_TOK;

    __shared__ bf16 sA[BM * BK];
    __shared__ bf16 sB[BN * BK];

    int tidx = threadIdx.x;
    int lane = tidx & 63;
    int wv = tidx >> 6;
    int wm = wv >> 1, wn = wv & 1;

    f32x4 acc[2][2];
#pragma unroll
    for (int i = 0; i < 2; i++)
#pragma unroll
        for (int j = 0; j < 2; j++) acc[i][j] = (f32x4){0.f, 0.f, 0.f, 0.f};

    long arow_off[2], brow_off[2];
    int lds_off[2];
#pragma unroll
    for (int c2 = 0; c2 < 2; c2++) {
        int c = tidx + c2 * 256;
        int row = c >> 3, col8 = c & 7;
        arow_off[c2] = (long)(m0 + row) * ldh + col8 * 8;
        brow_off[c2] = (long)(n0 + row) * Kdim + col8 * 8;
        lds_off[c2] = row * BK + ((col8 ^ (row & 7)) << 3);
    }

    // Prefetch registers: A is bf16 (2 x bf16x8), B is f32 (4 x f32x4).
    bf16x8 pA[2];
    f32x4 pB[2][2];
#pragma unroll
    for (int c2 = 0; c2 < 2; c2++) {
        pA[c2] = *(const bf16x8*)&A[arow_off[c2]];
        pB[c2][0] = *(const f32x4*)&B[brow_off[c2]];
        pB[c2][1] = *(const f32x4*)&B[brow_off[c2] + 4];
    }

    const int ktiles = Kdim / BK;
    for (int kt = 0; kt < ktiles; kt++) {
        __syncthreads();
#pragma unroll
        for (int c2 = 0; c2 < 2; c2++) {
            *(bf16x8*)&sA[lds_off[c2]] = pA[c2];
            *(bf16x8*)&sB[lds_off[c2]] = cvt8v(pB[c2][0], pB[c2][1]);
        }
        {
            int k0n = (kt + 1 < ktiles) ? (kt + 1) * BK : kt * BK;
#pragma unroll
            for (int c2 = 0; c2 < 2; c2++) {
                pA[c2] = *(const bf16x8*)&A[arow_off[c2] + k0n];
                pB[c2][0] = *(const f32x4*)&B[brow_off[c2] + k0n];
                pB[c2][1] = *(const f32x4*)&B[brow_off[c2] + k0n + 4];
            }
        }
        __syncthreads();
        int quad = lane >> 4, l16 = lane & 15;
        bf16x8 aF[2][2], bF[2][2];
#pragma unroll
        for (int mt = 0; mt < 2; mt++) {
            int r = wm * 32 + mt * 16 + l16;
            int rb = r * BK, rx = r & 7;
#pragma unroll
            for (int ks = 0; ks < 2; ks++)
                aF[mt][ks] = *(const bf16x8*)&sA[rb + (((ks * 4 + quad) ^ rx) << 3)];
        }
#pragma unroll
        for (int nt = 0; nt < 2; nt++) {
            int r = wn * 32 + nt * 16 + l16;
            int rb = r * BK, rx = r & 7;
#pragma unroll
            for (int ks = 0; ks < 2; ks++)
                bF[nt][ks] = *(const bf16x8*)&sB[rb + (((ks * 4 + quad) ^ rx) << 3)];
        }
#pragma unroll
        for (int ks = 0; ks < 2; ks++)
#pragma unroll
            for (int mt = 0; mt < 2; mt++)
#pragma unroll
                for (int nt = 0; nt < 2; nt++)
                    acc[mt][nt] = __builtin_amdgcn_mfma_f32_16x16x32_bf16(aF[mt][ks], bF[nt][ks], acc[mt][nt], 0, 0, 0);
    }

    int quad = lane >> 4, l16 = lane & 15;
#pragma unroll
    for (int mt = 0; mt < 2; mt++) {
#pragma unroll
        for (int r = 0; r < 4; r++) {
            int row = m0 + wm * 32 + mt * 16 + quad * 4 + r;
            if (row < count) {
#pragma unroll
                for (int nt = 0; nt < 2; nt++) {
                    int col = n0 + wn * 32 + nt * 16 + l16;
                    float v = acc[mt][nt][r];
                    if constexpr (GATHER) {
                        int tok = tid_p[row];
                        atomicAdd(&out[(long)tok * H_DIM + col], v);
                    } else {
                        out[(long)row * H_DIM + col] = v;
                    }
                }
            }
        }
    }
}

// ---------------------------------------------------------------------------
// Workspace layout (bytes):
//   0        counts        (E ints, padded to 256)
//   256      tok_id        (E*T ints   = 32768)
//   33024    tok_w         (E*T floats = 32768)
//   65792    hshared       (T*IS bf16  = 2883584)
//   2949376  hrouted       (E*T*I bf16 = 23068672)
//   total ~26.0 MB
// ---------------------------------------------------------------------------
extern "C" void kernel_launch(void* const* d_in, const int* in_sizes, int n_in,
                              void* d_out, int out_size, void* d_ws, size_t ws_size,
                              hipStream_t stream)
{
    const float* x              = (const float*)d_in[0];
    const float* gate_w         = (const float*)d_in[1];
    const float* w_gate_up      = (const float*)d_in[2];
    const float* w_down         = (const float*)d_in[3];
    const float* shared_gate_up = (const float*)d_in[4];
    const float* shared_down    = (const float*)d_in[5];
    float* out = (float*)d_out;

    char* ws = (char*)d_ws;
    int*   counts  = (int*)(ws + 0);
    int*   tok_id  = (int*)(ws + 256);
    float* tok_w   = (float*)(ws + 33024);
    bf16*  hshared = (bf16*)(ws + 65792);
    bf16*  hrouted = (bf16*)(ws + 2949376);

    hipMemsetAsync(counts, 0, E_NUM * sizeof(int), stream);

    router_kernel<<<T_TOK, 64, 0, stream>>>(x, gate_w, counts, tok_id, tok_w);

    // shared gate_up: N=IS, K=H; identity rows. 44x8 = 352 blocks.
    gateup_kernel<false><<<dim3(IS_DIM / BN, T_TOK / BM, 1), 256, 0, stream>>>(
        x, shared_gate_up, 0L, IS_DIM, hshared, 0L, IS_DIM, nullptr, nullptr, nullptr);

    // routed gate_up: N=I, K=H; gathered rows, combine weight fused.
    gateup_kernel<true><<<dim3(I_DIM / BN, T_TOK / BM, E_NUM), 256, 0, stream>>>(
        x, w_gate_up, (long)2 * I_DIM * H_DIM, I_DIM, hrouted, (long)T_TOK * I_DIM, I_DIM,
        counts, tok_id, tok_w);

    // shared down: K=IS, N=H; plain store initializes out fully. 32x8 = 256 blocks.
    down_kernel<false><<<dim3(H_DIM / BN, T_TOK / BM, 1), 256, 0, stream>>>(
        hshared, 0L, IS_DIM, IS_DIM, shared_down, 0L, out, nullptr, nullptr);

    // routed down: K=I, N=H; atomicAdd scatter by token.
    down_kernel<true><<<dim3(H_DIM / BN, T_TOK / BM, E_NUM), 256, 0, stream>>>(
        hrouted, (long)T_TOK * I_DIM, I_DIM, I_DIM, w_down, (long)H_DIM * I_DIM, out,
        counts, tok_id);
}